// Round 6
// baseline (2055.382 us; speedup 1.0000x reference)
//
#include <hip/hip_runtime.h>
#include <cstdint>

// ---------------------------------------------------------------------------
// ChartParser: span scores + per-batch CKY DP + backtrack.
// B=64, S=256, D=H=1024. Output: int32 [2][B][S] (lefts then rights).
// Round 6: (a) 6 limb products instead of 8 (drop m*l, l*m ~ 2^-24);
// (b) lefts+rights fused into one N=2048 MFMA GEMM; (c) gemmnt on MFMA with
// in-kernel split of both operands; (d) CKY i-quad with right operand read as
// two aligned ds_read_b128 + uniform select (fixes round-4's 8-way conflicts).
// ---------------------------------------------------------------------------

#define Bb 64
#define Ss 256
#define Dd 1024
#define Hh 1024

typedef __attribute__((ext_vector_type(8))) short bf16x8;
typedef __attribute__((ext_vector_type(4))) float f32x4;

__device__ __forceinline__ unsigned short bf16_rne(float x) {
  unsigned u = __float_as_uint(x);
  unsigned r = (u + 0x7FFFu + ((u >> 16) & 1u)) >> 16;
  return (unsigned short)r;
}
__device__ __forceinline__ float bf16_to_f(unsigned short h) {
  return __uint_as_float(((unsigned)h) << 16);
}

// ---------------------------------------------------------------------------
// Weight split+transpose: W fp32 [1024 rows k, ld ldw] -> O bf16 [n][k] rows,
// limb planes at +0, +plane, +2*plane. h+m+l covers fp32 exactly (24 bits).
// ---------------------------------------------------------------------------
__global__ __launch_bounds__(256) void splitw_kernel(
    const float* __restrict__ W, int ldw, unsigned short* __restrict__ O,
    long long plane) {
  int idx = blockIdx.x * 256 + threadIdx.x;  // n*1024 + k
  int n = idx >> 10, k = idx & 1023;
  float x = W[(long long)k * ldw + n];
  unsigned short h = bf16_rne(x);
  float r = x - bf16_to_f(h);
  unsigned short m = bf16_rne(r);
  float r2 = r - bf16_to_f(m);
  unsigned short l = bf16_rne(r2);
  O[idx] = h;
  O[plane + idx] = m;
  O[2 * plane + idx] = l;
}

// Extract Wbil's bias row / col / corner.
__global__ __launch_bounds__(256) void bilvec_kernel(
    const float* __restrict__ Wbil, float* __restrict__ brow,
    float* __restrict__ bcol, float* __restrict__ corner) {
  int i = blockIdx.x * 256 + threadIdx.x;  // 0..1023
  brow[i] = Wbil[1024 * 1025 + i];
  bcol[i] = Wbil[i * 1025 + 1024];
  if (i == 0) corner[0] = Wbil[1024 * 1025 + 1024];
}

__device__ __forceinline__ void pack8(char* dst, const unsigned short* v) {
  uint4 u;
  u.x = (unsigned)v[0] | ((unsigned)v[1] << 16);
  u.y = (unsigned)v[2] | ((unsigned)v[3] << 16);
  u.z = (unsigned)v[4] | ((unsigned)v[5] << 16);
  u.w = (unsigned)v[6] | ((unsigned)v[7] << 16);
  *(uint4*)dst = u;
}

// split 16 fp32 into 3x16 bf16 limbs and store (swizzled) to 3 LDS planes
__device__ __forceinline__ void split_store16(const float* xs, char* lds,
                                              int base, int wa0, int wa1) {
  unsigned short hs[16], ms[16], ls[16];
#pragma unroll
  for (int i = 0; i < 16; ++i) {
    hs[i] = bf16_rne(xs[i]);
    float r = xs[i] - bf16_to_f(hs[i]);
    ms[i] = bf16_rne(r);
    float r2 = r - bf16_to_f(ms[i]);
    ls[i] = bf16_rne(r2);
  }
  pack8(&lds[base + wa0], hs);
  pack8(&lds[base + wa1], hs + 8);
  pack8(&lds[base + 8192 + wa0], ms);
  pack8(&lds[base + 8192 + wa1], ms + 8);
  pack8(&lds[base + 16384 + wa0], ls);
  pack8(&lds[base + 16384 + wa1], ls + 8);
}

// 6-product accumulate for one (nf) column of B-frags against af[3][4]
#define MFMA6(afv, b0, b1, b2, accs, nf)                                     \
  {                                                                          \
    _Pragma("unroll") for (int mf = 0; mf < 4; ++mf) accs[mf][nf] =          \
        __builtin_amdgcn_mfma_f32_16x16x32_bf16(afv[0][mf], b0,              \
                                                accs[mf][nf], 0, 0, 0);      \
    _Pragma("unroll") for (int mf = 0; mf < 4; ++mf) accs[mf][nf] =          \
        __builtin_amdgcn_mfma_f32_16x16x32_bf16(afv[0][mf], b1,              \
                                                accs[mf][nf], 0, 0, 0);      \
    _Pragma("unroll") for (int mf = 0; mf < 4; ++mf) accs[mf][nf] =          \
        __builtin_amdgcn_mfma_f32_16x16x32_bf16(afv[1][mf], b0,              \
                                                accs[mf][nf], 0, 0, 0);      \
    _Pragma("unroll") for (int mf = 0; mf < 4; ++mf) accs[mf][nf] =          \
        __builtin_amdgcn_mfma_f32_16x16x32_bf16(afv[0][mf], b2,              \
                                                accs[mf][nf], 0, 0, 0);      \
    _Pragma("unroll") for (int mf = 0; mf < 4; ++mf) accs[mf][nf] =          \
        __builtin_amdgcn_mfma_f32_16x16x32_bf16(afv[2][mf], b0,              \
                                                accs[mf][nf], 0, 0, 0);      \
    _Pragma("unroll") for (int mf = 0; mf < 4; ++mf) accs[mf][nf] =          \
        __builtin_amdgcn_mfma_f32_16x16x32_bf16(afv[1][mf], b1,              \
                                                accs[mf][nf], 0, 0, 0);      \
  }

// ---------------------------------------------------------------------------
// MFMA GEMM (NN): out = act(A[M,1024]_fp32 * Bsp + bias). Bsp is pre-split
// bf16 [n][k] with limb planes at stride bplane. Tile 128x128, BK=32,
// 256 threads, wave-tile 64x64 (4x4 frags of mfma_f32_16x16x32_bf16).
// If n0 >= 1024 the block writes C1/bias1 at col-1024 (fused dual output).
// ---------------------------------------------------------------------------
template <bool LEAKY>
__global__ __launch_bounds__(256, 3) void gemm_mfma_kernel(
    const float* __restrict__ A, const unsigned short* __restrict__ Bsp,
    long long bplane, float* __restrict__ C0, float* __restrict__ C1,
    const float* __restrict__ bias0, const float* __restrict__ bias1) {
  const int m0 = blockIdx.y * 128;
  const int n0 = blockIdx.x * 128;
  __shared__ __align__(16) char lds[49152];
  const int t = threadIdx.x;
  const int L = t & 63, w = t >> 6, q = L >> 4, l15 = L & 15;

  const int ar = t >> 1, ah = t & 1;
  const float* aptr = A + (long long)(m0 + ar) * 1024 + ah * 16;
  const int phiA = ((ar >> 1) ^ (ar >> 3)) & 3;
  const int wa0 = ar * 64 + (((2 * ah + 0) ^ phiA) << 4);
  const int wa1 = ar * 64 + (((2 * ah + 1) ^ phiA) << 4);

  int offA0[4], offB0[4];
#pragma unroll
  for (int f = 0; f < 4; ++f) {
    int rowa = ((w & 1) << 6) + (f << 4) + l15;
    offA0[f] = rowa * 64 + ((q ^ (((rowa >> 1) ^ (rowa >> 3)) & 3)) << 4);
    int rowb = ((w >> 1) << 6) + (f << 4) + l15;
    offB0[f] =
        24576 + rowb * 64 + ((q ^ (((rowb >> 1) ^ (rowb >> 3)) & 3)) << 4);
  }

  f32x4 acc[4][4];
#pragma unroll
  for (int i = 0; i < 4; ++i)
#pragma unroll
    for (int j = 0; j < 4; ++j) acc[i][j] = (f32x4){0.f, 0.f, 0.f, 0.f};

  for (int k0 = 0; k0 < 1024; k0 += 32) {
    // B staging: 6 x 16B per thread (pre-split bf16, swizzled dest)
#pragma unroll
    for (int j = 0; j < 6; ++j) {
      int fc = t + (j << 8);  // 0..1535
      int s = fc >> 9, r = (fc >> 2) & 127, sc = fc & 3;
      const unsigned short* bs = Bsp + s * bplane;
      uint4 bv =
          *(const uint4*)(bs + (long long)(n0 + r) * 1024 + k0 + (sc << 3));
      int phi = ((r >> 1) ^ (r >> 3)) & 3;
      *(uint4*)&lds[24576 + s * 8192 + r * 64 + ((sc ^ phi) << 4)] = bv;
    }
    // A staging: 16 fp32 -> 3 x 16 bf16 limbs
    {
      float4 a0 = *(const float4*)(aptr + k0);
      float4 a1 = *(const float4*)(aptr + k0 + 4);
      float4 a2 = *(const float4*)(aptr + k0 + 8);
      float4 a3 = *(const float4*)(aptr + k0 + 12);
      float xs[16] = {a0.x, a0.y, a0.z, a0.w, a1.x, a1.y, a1.z, a1.w,
                      a2.x, a2.y, a2.z, a2.w, a3.x, a3.y, a3.z, a3.w};
      split_store16(xs, lds, 0, wa0, wa1);
    }
    __syncthreads();
    bf16x8 af[3][4];
#pragma unroll
    for (int s = 0; s < 3; ++s)
#pragma unroll
      for (int f = 0; f < 4; ++f)
        af[s][f] = *(const bf16x8*)&lds[s * 8192 + offA0[f]];
#pragma unroll
    for (int nf = 0; nf < 4; ++nf) {
      bf16x8 b0 = *(const bf16x8*)&lds[offB0[nf]];
      bf16x8 b1 = *(const bf16x8*)&lds[8192 + offB0[nf]];
      bf16x8 b2 = *(const bf16x8*)&lds[16384 + offB0[nf]];
      MFMA6(af, b0, b1, b2, acc, nf);
    }
    __syncthreads();
  }

  const bool isR = (n0 >= 1024);
  float* Co = isR ? C1 : C0;
  const float* bp = isR ? bias1 : bias0;
  const int nc0 = n0 & 1023;
#pragma unroll
  for (int nf = 0; nf < 4; ++nf) {
    int col = nc0 + ((w >> 1) << 6) + (nf << 4) + l15;
    float bz = bp[col];
#pragma unroll
    for (int mf = 0; mf < 4; ++mf) {
#pragma unroll
      for (int r = 0; r < 4; ++r) {
        int row = m0 + ((w & 1) << 6) + (mf << 4) + (q << 2) + r;
        float x = acc[mf][nf][r] + bz;
        if (LEAKY) x = (x > 0.f) ? x : 0.1f * x;
        Co[(long long)row * 1024 + col] = x;
      }
    }
  }
}

// ---------------------------------------------------------------------------
// Batched NT GEMM on MFMA: C[b] = tmpA[b] * rights[b]^T + rowAdd + scal.
// Both operands fp32, split in-kernel. Tile 128x128, grid (2,2,64).
// ---------------------------------------------------------------------------
__global__ __launch_bounds__(256, 3) void gemmnt_mfma_kernel(
    const float* __restrict__ A, const float* __restrict__ B,
    float* __restrict__ C, const float* __restrict__ rowAdd,
    const float* __restrict__ scal) {
  const int bz = blockIdx.z;
  A += (long long)bz * 256 * 1024;
  B += (long long)bz * 256 * 1024;
  C += (long long)bz * 256 * 256;
  const int m0 = blockIdx.y * 128;
  const int n0 = blockIdx.x * 128;
  __shared__ __align__(16) char lds[49152];
  const int t = threadIdx.x;
  const int L = t & 63, w = t >> 6, q = L >> 4, l15 = L & 15;

  const int ar = t >> 1, ah = t & 1;
  const float* aptr = A + (long long)(m0 + ar) * 1024 + ah * 16;
  const float* bptr = B + (long long)(n0 + ar) * 1024 + ah * 16;
  const int phiA = ((ar >> 1) ^ (ar >> 3)) & 3;
  const int wa0 = ar * 64 + (((2 * ah + 0) ^ phiA) << 4);
  const int wa1 = ar * 64 + (((2 * ah + 1) ^ phiA) << 4);

  int offA0[4], offB0[4];
#pragma unroll
  for (int f = 0; f < 4; ++f) {
    int rowa = ((w & 1) << 6) + (f << 4) + l15;
    offA0[f] = rowa * 64 + ((q ^ (((rowa >> 1) ^ (rowa >> 3)) & 3)) << 4);
    int rowb = ((w >> 1) << 6) + (f << 4) + l15;
    offB0[f] =
        24576 + rowb * 64 + ((q ^ (((rowb >> 1) ^ (rowb >> 3)) & 3)) << 4);
  }

  f32x4 acc[4][4];
#pragma unroll
  for (int i = 0; i < 4; ++i)
#pragma unroll
    for (int j = 0; j < 4; ++j) acc[i][j] = (f32x4){0.f, 0.f, 0.f, 0.f};

  for (int k0 = 0; k0 < 1024; k0 += 32) {
    {
      float4 a0 = *(const float4*)(aptr + k0);
      float4 a1 = *(const float4*)(aptr + k0 + 4);
      float4 a2 = *(const float4*)(aptr + k0 + 8);
      float4 a3 = *(const float4*)(aptr + k0 + 12);
      float xs[16] = {a0.x, a0.y, a0.z, a0.w, a1.x, a1.y, a1.z, a1.w,
                      a2.x, a2.y, a2.z, a2.w, a3.x, a3.y, a3.z, a3.w};
      split_store16(xs, lds, 0, wa0, wa1);
      float4 b0 = *(const float4*)(bptr + k0);
      float4 b1 = *(const float4*)(bptr + k0 + 4);
      float4 b2 = *(const float4*)(bptr + k0 + 8);
      float4 b3 = *(const float4*)(bptr + k0 + 12);
      float ys[16] = {b0.x, b0.y, b0.z, b0.w, b1.x, b1.y, b1.z, b1.w,
                      b2.x, b2.y, b2.z, b2.w, b3.x, b3.y, b3.z, b3.w};
      split_store16(ys, lds, 24576, wa0, wa1);
    }
    __syncthreads();
    bf16x8 af[3][4];
#pragma unroll
    for (int s = 0; s < 3; ++s)
#pragma unroll
      for (int f = 0; f < 4; ++f)
        af[s][f] = *(const bf16x8*)&lds[s * 8192 + offA0[f]];
#pragma unroll
    for (int nf = 0; nf < 4; ++nf) {
      bf16x8 b0 = *(const bf16x8*)&lds[offB0[nf]];
      bf16x8 b1 = *(const bf16x8*)&lds[8192 + offB0[nf]];
      bf16x8 b2 = *(const bf16x8*)&lds[16384 + offB0[nf]];
      MFMA6(af, b0, b1, b2, acc, nf);
    }
    __syncthreads();
  }

  const float sc_add = scal[0];
#pragma unroll
  for (int mf = 0; mf < 4; ++mf) {
#pragma unroll
    for (int r = 0; r < 4; ++r) {
      int row = m0 + ((w & 1) << 6) + (mf << 4) + (q << 2) + r;
      float radd = sc_add + rowAdd[(long long)bz * 256 + row];
#pragma unroll
      for (int nf = 0; nf < 4; ++nf) {
        int col = n0 + ((w >> 1) << 6) + (nf << 4) + l15;
        C[(long long)row * 256 + col] = acc[mf][nf][r] + radd;
      }
    }
  }
}

// ---------------------------------------------------------------------------
// tmpb[i] = dot(lefts[i,:], Wbil[0:H, H]) + Wbil[H,H].  One wave per row.
// ---------------------------------------------------------------------------
__global__ __launch_bounds__(64) void colvec_kernel(
    const float* __restrict__ lefts, const float* __restrict__ bcol,
    const float* __restrict__ corner, float* __restrict__ tmpb) {
  int row = blockIdx.x;
  int lane = threadIdx.x;
  const float* a = lefts + (long long)row * Hh;
  float s = 0.f;
#pragma unroll
  for (int h = lane; h < Hh; h += 64) s = fmaf(a[h], bcol[h], s);
#pragma unroll
  for (int off = 32; off > 0; off >>= 1) s += __shfl_down(s, off, 64);
  if (lane == 0) tmpb[row] = s + corner[0];
}

// ---------------------------------------------------------------------------
// CKY + backtrack. One block per batch, 1024 threads. Chart in LDS, diag-major
// padded to 4-float diagonal starts: off(m) = 256m - 8a(a-1) - 4ab (a=m>>2,
// b=m&3), 33280 floats + guard. Each thread handles an i-QUAD: left operand =
// one aligned ds_read_b128; right operand = TWO aligned ds_read_b128 covering
// the unaligned 4-float window + uniform-shift select (round 4's scalar
// stride-4 b32 reads were the 8-way-conflict bug; b128 is lane-contiguous =>
// conflict-free). Adaptive m-groups G in {16,32,64}; ascending-(g,m) strict->
// combine preserves jnp.argmax first-max semantics. Backtrack from LDS.
// ---------------------------------------------------------------------------
__global__ __launch_bounds__(1024) void cky_kernel(
    const float* __restrict__ scores,  // [64][256][256]
    uint8_t* __restrict__ Sws,         // [64][33280] padded triangular
    int* __restrict__ out)             // [2][64][256] int32
{
  const int b = blockIdx.x;
  const int t = threadIdx.x;
  const int n = Ss;
  const float* sc = scores + (long long)b * n * n;
  uint8_t* SP = Sws + (long long)b * 33280;

  __shared__ __align__(16) float Dch[33296];  // padded chart + guard
  __shared__ __align__(16) float pv[4096];    // partials: [G][4<<lgQ]
  __shared__ uint8_t pmv[4096];
  __shared__ int stk[256];

  if (t < n) {
    out[b * n + t] = 0;  // slot n-1 must stay 0 (torch.zeros semantics)
    out[Bb * n + b * n + t] = 0;
    Dch[t] = 0.f;  // width-0 diagonal (off(0)=0, len 256)
  }
  __syncthreads();

  int offw = 256;  // off(1)
  for (int w = 1; w < n; ++w) {
    const int nv = n - w;
    const int NQ = (nv + 3) >> 2;                       // i-quads needed
    const int lgQ = (NQ > 32) ? 6 : (NQ > 16) ? 5 : 4;  // quad slots = 1<<lgQ
    const int G = 1024 >> lgQ;                          // m-groups (16/32/64)
    const int u = t & ((1 << lgQ) - 1);
    const int g = t >> lgQ;
    const int qi = u * 4;

    float scv = 0.f;
    if (t < nv) scv = sc[t * (n + 1) + w];

    const int wG = (w + G - 1) >> (10 - lgQ);  // ceil(w/G)
    const int ml = g * wG;
    const int mh = (w < ml + wG) ? w : (ml + wG);

    float bv0 = -3.0e38f, bv1 = -3.0e38f, bv2 = -3.0e38f, bv3 = -3.0e38f;
    int bm0 = 0, bm1 = 0, bm2 = 0, bm3 = 0;
    if (qi < nv && ml < mh) {
      int a2 = ml >> 2;
      int al = (ml << 8) - 8 * a2 * (a2 - 1) - 4 * a2 * (ml & 3) + qi;
      int kr = w - 1 - ml;
      int a3 = kr >> 2;
      int arB = (kr << 8) - 8 * a3 * (a3 - 1) - 4 * a3 * (kr & 3);  // off(kr)
#pragma unroll 2
      for (int m = ml; m < mh; ++m) {
        float4 lv = *(const float4*)(Dch + al);
        const int col = qi + m + 1;
        const int wb = arB + (col & ~3);
        float4 f0 = *(const float4*)(Dch + wb);
        float4 f1 = *(const float4*)(Dch + wb + 4);
        const int s = col & 3;  // uniform within group
        float r0 = (s == 0) ? f0.x : (s == 1) ? f0.y : (s == 2) ? f0.z : f0.w;
        float r1 = (s == 0) ? f0.y : (s == 1) ? f0.z : (s == 2) ? f0.w : f1.x;
        float r2 = (s == 0) ? f0.z : (s == 1) ? f0.w : (s == 2) ? f1.x : f1.y;
        float r3 = (s == 0) ? f0.w : (s == 1) ? f1.x : (s == 2) ? f1.y : f1.z;
        float c0 = lv.x + r0, c1 = lv.y + r1, c2 = lv.z + r2, c3 = lv.w + r3;
        if (c0 > bv0) { bv0 = c0; bm0 = m; }  // strict > = first max
        if (c1 > bv1) { bv1 = c1; bm1 = m; }
        if (c2 > bv2) { bv2 = c2; bm2 = m; }
        if (c3 > bv3) { bv3 = c3; bm3 = m; }
        al += 256 - (m & ~3);          // off(m+1) - off(m)
        arB -= 256 - ((kr - 1) & ~3);  // off(kr-1)
        --kr;
      }
    }
    const int base = (g << (lgQ + 2)) + qi;
    *(float4*)(pv + base) = make_float4(bv0, bv1, bv2, bv3);
    *(uchar4*)(pmv + base) = make_uchar4((unsigned char)bm0, (unsigned char)bm1,
                                         (unsigned char)bm2,
                                         (unsigned char)bm3);
    __syncthreads();

    if (t < nv) {
      float bb = pv[t];
      int bm = pmv[t];
#pragma unroll 4
      for (int g2 = 1; g2 < G; ++g2) {
        const int idx = (g2 << (lgQ + 2)) + t;
        float v = pv[idx];
        if (v > bb) {  // ascending g + strict > = first max overall
          bb = v;
          bm = pmv[idx];
        }
      }
      Dch[offw + t] = scv + bb;
      SP[offw + t] = (uint8_t)bm;
    }
    __syncthreads();
    offw += (nv + 3) & ~3;
  }

  // backtrack: copy SP into the dead chart's LDS, then serial chase
  uint8_t* spl = (uint8_t*)Dch;
  for (int idx = t; idx < 33280; idx += 1024) spl[idx] = SP[idx];
  __syncthreads();
  if (t == 0) {
    int top = 0;
    stk[top++] = (0 << 16) | (n - 1);
    int cnt = 0;
    for (int step = 0; step < n - 1; ++step) {
      if (top > 0) {
        int ij = stk[--top];
        int ii = ij >> 16, jj = ij & 0xffff;
        out[b * n + cnt] = ii;
        out[Bb * n + b * n + cnt] = jj;
        ++cnt;
        int k = jj - ii;
        int a4 = k >> 2;
        int offk = (k << 8) - 8 * a4 * (a4 - 1) - 4 * a4 * (k & 3);
        int s = ii + (int)spl[offk + ii];
        stk[top] = (ii << 16) | s;
        if (s > ii) ++top;
        stk[top] = ((s + 1) << 16) | jj;
        if (jj > s + 1) ++top;
      }
    }
  }
}

// ---------------------------------------------------------------------------
// Launch
// ---------------------------------------------------------------------------
extern "C" void kernel_launch(void* const* d_in, const int* in_sizes, int n_in,
                              void* d_out, int out_size, void* d_ws,
                              size_t ws_size, hipStream_t stream) {
  const float* X = (const float*)d_in[0];     // [64,256,1024]
  const float* Wl = (const float*)d_in[2];    // [1024,1024]
  const float* bl = (const float*)d_in[3];    // [1024]
  const float* Wr = (const float*)d_in[4];
  const float* br = (const float*)d_in[5];
  const float* Wbil = (const float*)d_in[6];  // [1025,1025]
  const float* bbil = (const float*)d_in[7];  // scalar
  int* out = (int*)d_out;

  // workspace layout
  float* ws = (float*)d_ws;
  float* lefts = ws;                          // 16777216 f
  float* rights = lefts + 16777216;           // 16777216 f
  float* tmpA = rights + 16777216;            // 16777216 f
  float* scoresP = tmpA + 16777216;           // 4194304 f
  float* tmpb = scoresP + 4194304;            // 16384 f
  float* browp = tmpb + 16384;                // 1024 f
  float* bcolp = browp + 1024;                // 1024 f
  float* cornerp = bcolp + 1024;              // 4 f
  unsigned short* Wlrt = (unsigned short*)(cornerp + 4);  // 3 x 2M bf16
  unsigned short* Wct = Wlrt + 3LL * 2097152;             // 3 x 1M bf16
  uint8_t* SPp = (uint8_t*)(Wct + 3LL * 1048576);         // 64x33280 u8

  // weight splits (+ Wbil bias vectors)
  splitw_kernel<<<dim3(4096), 256, 0, stream>>>(Wl, 1024, Wlrt, 2097152);
  splitw_kernel<<<dim3(4096), 256, 0, stream>>>(Wr, 1024, Wlrt + 1048576,
                                                2097152);
  splitw_kernel<<<dim3(4096), 256, 0, stream>>>(Wbil, 1025, Wct, 1048576);
  bilvec_kernel<<<dim3(4), 256, 0, stream>>>(Wbil, browp, bcolp, cornerp);

  // fused lefts|rights GEMM: N=2048
  dim3 gLR(16, 128);
  gemm_mfma_kernel<true><<<gLR, 256, 0, stream>>>(X, Wlrt, 2097152LL, lefts,
                                                  rights, bl, br);

  colvec_kernel<<<dim3(16384), 64, 0, stream>>>(lefts, bcolp, cornerp, tmpb);

  dim3 gA(8, 128);
  gemm_mfma_kernel<false><<<gA, 256, 0, stream>>>(lefts, Wct, 1048576LL, tmpA,
                                                  tmpA, browp, browp);

  dim3 g3(2, 2, 64);
  gemmnt_mfma_kernel<<<g3, 256, 0, stream>>>(tmpA, rights, scoresP, tmpb,
                                             bbil);

  cky_kernel<<<dim3(Bb), dim3(1024), 0, stream>>>(scoresP, SPp, out);
}

// Round 7
// 1445.833 us; speedup vs baseline: 1.4216x; 1.4216x over previous
//
#include <hip/hip_runtime.h>
#include <cstdint>

// ---------------------------------------------------------------------------
// ChartParser: span scores + per-batch CKY DP + backtrack.
// B=64, S=256, D=H=1024. Output: int32 [2][B][S] (lefts then rights).
// Round 7: consolidation. CKY = round-3 kernel (b32 stride-1 reads, 0 bank
// conflicts, LDS-pipe-bound ~600us — both b128-quad variants regressed:
// full-wave ds_read_b128 decomposes per-dword -> intrinsic 8-lane/bank
// aliasing at lane-stride-16B; unfixable by chunk swizzle). GEMM side =
// round-6 pipeline (6 limb products, fused LR N=2048, MFMA-NT), measured
// 880us GEMM-side vs round-5's 1034.
// ---------------------------------------------------------------------------

#define Bb 64
#define Ss 256
#define Dd 1024
#define Hh 1024

typedef __attribute__((ext_vector_type(8))) short bf16x8;
typedef __attribute__((ext_vector_type(4))) float f32x4;

__device__ __forceinline__ unsigned short bf16_rne(float x) {
  unsigned u = __float_as_uint(x);
  unsigned r = (u + 0x7FFFu + ((u >> 16) & 1u)) >> 16;
  return (unsigned short)r;
}
__device__ __forceinline__ float bf16_to_f(unsigned short h) {
  return __uint_as_float(((unsigned)h) << 16);
}

// ---------------------------------------------------------------------------
// Weight split+transpose: W fp32 [1024 rows k, ld ldw] -> O bf16 [n][k] rows,
// limb planes at +0, +plane, +2*plane. h+m+l covers fp32 exactly (24 bits).
// ---------------------------------------------------------------------------
__global__ __launch_bounds__(256) void splitw_kernel(
    const float* __restrict__ W, int ldw, unsigned short* __restrict__ O,
    long long plane) {
  int idx = blockIdx.x * 256 + threadIdx.x;  // n*1024 + k
  int n = idx >> 10, k = idx & 1023;
  float x = W[(long long)k * ldw + n];
  unsigned short h = bf16_rne(x);
  float r = x - bf16_to_f(h);
  unsigned short m = bf16_rne(r);
  float r2 = r - bf16_to_f(m);
  unsigned short l = bf16_rne(r2);
  O[idx] = h;
  O[plane + idx] = m;
  O[2 * plane + idx] = l;
}

// Extract Wbil's bias row / col / corner.
__global__ __launch_bounds__(256) void bilvec_kernel(
    const float* __restrict__ Wbil, float* __restrict__ brow,
    float* __restrict__ bcol, float* __restrict__ corner) {
  int i = blockIdx.x * 256 + threadIdx.x;  // 0..1023
  brow[i] = Wbil[1024 * 1025 + i];
  bcol[i] = Wbil[i * 1025 + 1024];
  if (i == 0) corner[0] = Wbil[1024 * 1025 + 1024];
}

__device__ __forceinline__ void pack8(char* dst, const unsigned short* v) {
  uint4 u;
  u.x = (unsigned)v[0] | ((unsigned)v[1] << 16);
  u.y = (unsigned)v[2] | ((unsigned)v[3] << 16);
  u.z = (unsigned)v[4] | ((unsigned)v[5] << 16);
  u.w = (unsigned)v[6] | ((unsigned)v[7] << 16);
  *(uint4*)dst = u;
}

// split 16 fp32 into 3x16 bf16 limbs and store (swizzled) to 3 LDS planes
__device__ __forceinline__ void split_store16(const float* xs, char* lds,
                                              int base, int wa0, int wa1) {
  unsigned short hs[16], ms[16], ls[16];
#pragma unroll
  for (int i = 0; i < 16; ++i) {
    hs[i] = bf16_rne(xs[i]);
    float r = xs[i] - bf16_to_f(hs[i]);
    ms[i] = bf16_rne(r);
    float r2 = r - bf16_to_f(ms[i]);
    ls[i] = bf16_rne(r2);
  }
  pack8(&lds[base + wa0], hs);
  pack8(&lds[base + wa1], hs + 8);
  pack8(&lds[base + 8192 + wa0], ms);
  pack8(&lds[base + 8192 + wa1], ms + 8);
  pack8(&lds[base + 16384 + wa0], ls);
  pack8(&lds[base + 16384 + wa1], ls + 8);
}

// 6-product accumulate for one (nf) column of B-frags against af[3][4]
#define MFMA6(afv, b0, b1, b2, accs, nf)                                     \
  {                                                                          \
    _Pragma("unroll") for (int mf = 0; mf < 4; ++mf) accs[mf][nf] =          \
        __builtin_amdgcn_mfma_f32_16x16x32_bf16(afv[0][mf], b0,              \
                                                accs[mf][nf], 0, 0, 0);      \
    _Pragma("unroll") for (int mf = 0; mf < 4; ++mf) accs[mf][nf] =          \
        __builtin_amdgcn_mfma_f32_16x16x32_bf16(afv[0][mf], b1,              \
                                                accs[mf][nf], 0, 0, 0);      \
    _Pragma("unroll") for (int mf = 0; mf < 4; ++mf) accs[mf][nf] =          \
        __builtin_amdgcn_mfma_f32_16x16x32_bf16(afv[1][mf], b0,              \
                                                accs[mf][nf], 0, 0, 0);      \
    _Pragma("unroll") for (int mf = 0; mf < 4; ++mf) accs[mf][nf] =          \
        __builtin_amdgcn_mfma_f32_16x16x32_bf16(afv[0][mf], b2,              \
                                                accs[mf][nf], 0, 0, 0);      \
    _Pragma("unroll") for (int mf = 0; mf < 4; ++mf) accs[mf][nf] =          \
        __builtin_amdgcn_mfma_f32_16x16x32_bf16(afv[2][mf], b0,              \
                                                accs[mf][nf], 0, 0, 0);      \
    _Pragma("unroll") for (int mf = 0; mf < 4; ++mf) accs[mf][nf] =          \
        __builtin_amdgcn_mfma_f32_16x16x32_bf16(afv[1][mf], b1,              \
                                                accs[mf][nf], 0, 0, 0);      \
  }

// ---------------------------------------------------------------------------
// MFMA GEMM (NN): out = act(A[M,1024]_fp32 * Bsp + bias). Bsp is pre-split
// bf16 [n][k] with limb planes at stride bplane. Tile 128x128, BK=32,
// 256 threads, wave-tile 64x64 (4x4 frags of mfma_f32_16x16x32_bf16).
// If n0 >= 1024 the block writes C1/bias1 at col-1024 (fused dual output).
// ---------------------------------------------------------------------------
template <bool LEAKY>
__global__ __launch_bounds__(256, 3) void gemm_mfma_kernel(
    const float* __restrict__ A, const unsigned short* __restrict__ Bsp,
    long long bplane, float* __restrict__ C0, float* __restrict__ C1,
    const float* __restrict__ bias0, const float* __restrict__ bias1) {
  const int m0 = blockIdx.y * 128;
  const int n0 = blockIdx.x * 128;
  __shared__ __align__(16) char lds[49152];
  const int t = threadIdx.x;
  const int L = t & 63, w = t >> 6, q = L >> 4, l15 = L & 15;

  const int ar = t >> 1, ah = t & 1;
  const float* aptr = A + (long long)(m0 + ar) * 1024 + ah * 16;
  const int phiA = ((ar >> 1) ^ (ar >> 3)) & 3;
  const int wa0 = ar * 64 + (((2 * ah + 0) ^ phiA) << 4);
  const int wa1 = ar * 64 + (((2 * ah + 1) ^ phiA) << 4);

  int offA0[4], offB0[4];
#pragma unroll
  for (int f = 0; f < 4; ++f) {
    int rowa = ((w & 1) << 6) + (f << 4) + l15;
    offA0[f] = rowa * 64 + ((q ^ (((rowa >> 1) ^ (rowa >> 3)) & 3)) << 4);
    int rowb = ((w >> 1) << 6) + (f << 4) + l15;
    offB0[f] =
        24576 + rowb * 64 + ((q ^ (((rowb >> 1) ^ (rowb >> 3)) & 3)) << 4);
  }

  f32x4 acc[4][4];
#pragma unroll
  for (int i = 0; i < 4; ++i)
#pragma unroll
    for (int j = 0; j < 4; ++j) acc[i][j] = (f32x4){0.f, 0.f, 0.f, 0.f};

  for (int k0 = 0; k0 < 1024; k0 += 32) {
    // B staging: 6 x 16B per thread (pre-split bf16, swizzled dest)
#pragma unroll
    for (int j = 0; j < 6; ++j) {
      int fc = t + (j << 8);  // 0..1535
      int s = fc >> 9, r = (fc >> 2) & 127, sc = fc & 3;
      const unsigned short* bs = Bsp + s * bplane;
      uint4 bv =
          *(const uint4*)(bs + (long long)(n0 + r) * 1024 + k0 + (sc << 3));
      int phi = ((r >> 1) ^ (r >> 3)) & 3;
      *(uint4*)&lds[24576 + s * 8192 + r * 64 + ((sc ^ phi) << 4)] = bv;
    }
    // A staging: 16 fp32 -> 3 x 16 bf16 limbs
    {
      float4 a0 = *(const float4*)(aptr + k0);
      float4 a1 = *(const float4*)(aptr + k0 + 4);
      float4 a2 = *(const float4*)(aptr + k0 + 8);
      float4 a3 = *(const float4*)(aptr + k0 + 12);
      float xs[16] = {a0.x, a0.y, a0.z, a0.w, a1.x, a1.y, a1.z, a1.w,
                      a2.x, a2.y, a2.z, a2.w, a3.x, a3.y, a3.z, a3.w};
      split_store16(xs, lds, 0, wa0, wa1);
    }
    __syncthreads();
    bf16x8 af[3][4];
#pragma unroll
    for (int s = 0; s < 3; ++s)
#pragma unroll
      for (int f = 0; f < 4; ++f)
        af[s][f] = *(const bf16x8*)&lds[s * 8192 + offA0[f]];
#pragma unroll
    for (int nf = 0; nf < 4; ++nf) {
      bf16x8 b0 = *(const bf16x8*)&lds[offB0[nf]];
      bf16x8 b1 = *(const bf16x8*)&lds[8192 + offB0[nf]];
      bf16x8 b2 = *(const bf16x8*)&lds[16384 + offB0[nf]];
      MFMA6(af, b0, b1, b2, acc, nf);
    }
    __syncthreads();
  }

  const bool isR = (n0 >= 1024);
  float* Co = isR ? C1 : C0;
  const float* bp = isR ? bias1 : bias0;
  const int nc0 = n0 & 1023;
#pragma unroll
  for (int nf = 0; nf < 4; ++nf) {
    int col = nc0 + ((w >> 1) << 6) + (nf << 4) + l15;
    float bz = bp[col];
#pragma unroll
    for (int mf = 0; mf < 4; ++mf) {
#pragma unroll
      for (int r = 0; r < 4; ++r) {
        int row = m0 + ((w & 1) << 6) + (mf << 4) + (q << 2) + r;
        float x = acc[mf][nf][r] + bz;
        if (LEAKY) x = (x > 0.f) ? x : 0.1f * x;
        Co[(long long)row * 1024 + col] = x;
      }
    }
  }
}

// ---------------------------------------------------------------------------
// Batched NT GEMM on MFMA: C[b] = tmpA[b] * rights[b]^T + rowAdd + scal.
// Both operands fp32, split in-kernel. Tile 128x128, grid (2,2,64).
// ---------------------------------------------------------------------------
__global__ __launch_bounds__(256, 3) void gemmnt_mfma_kernel(
    const float* __restrict__ A, const float* __restrict__ B,
    float* __restrict__ C, const float* __restrict__ rowAdd,
    const float* __restrict__ scal) {
  const int bz = blockIdx.z;
  A += (long long)bz * 256 * 1024;
  B += (long long)bz * 256 * 1024;
  C += (long long)bz * 256 * 256;
  const int m0 = blockIdx.y * 128;
  const int n0 = blockIdx.x * 128;
  __shared__ __align__(16) char lds[49152];
  const int t = threadIdx.x;
  const int L = t & 63, w = t >> 6, q = L >> 4, l15 = L & 15;

  const int ar = t >> 1, ah = t & 1;
  const float* aptr = A + (long long)(m0 + ar) * 1024 + ah * 16;
  const float* bptr = B + (long long)(n0 + ar) * 1024 + ah * 16;
  const int phiA = ((ar >> 1) ^ (ar >> 3)) & 3;
  const int wa0 = ar * 64 + (((2 * ah + 0) ^ phiA) << 4);
  const int wa1 = ar * 64 + (((2 * ah + 1) ^ phiA) << 4);

  int offA0[4], offB0[4];
#pragma unroll
  for (int f = 0; f < 4; ++f) {
    int rowa = ((w & 1) << 6) + (f << 4) + l15;
    offA0[f] = rowa * 64 + ((q ^ (((rowa >> 1) ^ (rowa >> 3)) & 3)) << 4);
    int rowb = ((w >> 1) << 6) + (f << 4) + l15;
    offB0[f] =
        24576 + rowb * 64 + ((q ^ (((rowb >> 1) ^ (rowb >> 3)) & 3)) << 4);
  }

  f32x4 acc[4][4];
#pragma unroll
  for (int i = 0; i < 4; ++i)
#pragma unroll
    for (int j = 0; j < 4; ++j) acc[i][j] = (f32x4){0.f, 0.f, 0.f, 0.f};

  for (int k0 = 0; k0 < 1024; k0 += 32) {
    {
      float4 a0 = *(const float4*)(aptr + k0);
      float4 a1 = *(const float4*)(aptr + k0 + 4);
      float4 a2 = *(const float4*)(aptr + k0 + 8);
      float4 a3 = *(const float4*)(aptr + k0 + 12);
      float xs[16] = {a0.x, a0.y, a0.z, a0.w, a1.x, a1.y, a1.z, a1.w,
                      a2.x, a2.y, a2.z, a2.w, a3.x, a3.y, a3.z, a3.w};
      split_store16(xs, lds, 0, wa0, wa1);
      float4 b0 = *(const float4*)(bptr + k0);
      float4 b1 = *(const float4*)(bptr + k0 + 4);
      float4 b2 = *(const float4*)(bptr + k0 + 8);
      float4 b3 = *(const float4*)(bptr + k0 + 12);
      float ys[16] = {b0.x, b0.y, b0.z, b0.w, b1.x, b1.y, b1.z, b1.w,
                      b2.x, b2.y, b2.z, b2.w, b3.x, b3.y, b3.z, b3.w};
      split_store16(ys, lds, 24576, wa0, wa1);
    }
    __syncthreads();
    bf16x8 af[3][4];
#pragma unroll
    for (int s = 0; s < 3; ++s)
#pragma unroll
      for (int f = 0; f < 4; ++f)
        af[s][f] = *(const bf16x8*)&lds[s * 8192 + offA0[f]];
#pragma unroll
    for (int nf = 0; nf < 4; ++nf) {
      bf16x8 b0 = *(const bf16x8*)&lds[offB0[nf]];
      bf16x8 b1 = *(const bf16x8*)&lds[8192 + offB0[nf]];
      bf16x8 b2 = *(const bf16x8*)&lds[16384 + offB0[nf]];
      MFMA6(af, b0, b1, b2, acc, nf);
    }
    __syncthreads();
  }

  const float sc_add = scal[0];
#pragma unroll
  for (int mf = 0; mf < 4; ++mf) {
#pragma unroll
    for (int r = 0; r < 4; ++r) {
      int row = m0 + ((w & 1) << 6) + (mf << 4) + (q << 2) + r;
      float radd = sc_add + rowAdd[(long long)bz * 256 + row];
#pragma unroll
      for (int nf = 0; nf < 4; ++nf) {
        int col = n0 + ((w >> 1) << 6) + (nf << 4) + l15;
        C[(long long)row * 256 + col] = acc[mf][nf][r] + radd;
      }
    }
  }
}

// ---------------------------------------------------------------------------
// tmpb[i] = dot(lefts[i,:], Wbil[0:H, H]) + Wbil[H,H].  One wave per row.
// ---------------------------------------------------------------------------
__global__ __launch_bounds__(64) void colvec_kernel(
    const float* __restrict__ lefts, const float* __restrict__ bcol,
    const float* __restrict__ corner, float* __restrict__ tmpb) {
  int row = blockIdx.x;
  int lane = threadIdx.x;
  const float* a = lefts + (long long)row * Hh;
  float s = 0.f;
#pragma unroll
  for (int h = lane; h < Hh; h += 64) s = fmaf(a[h], bcol[h], s);
#pragma unroll
  for (int off = 32; off > 0; off >>= 1) s += __shfl_down(s, off, 64);
  if (lane == 0) tmpb[row] = s + corner[0];
}

// ---------------------------------------------------------------------------
// CKY + backtrack (round-3 kernel, measured 602us / 0 conflicts). One block
// per batch, 1024 threads. Chart in LDS, packed triangular diag-major;
// adaptive m-split (G,T) = (4,256)/(8,128)/(16,64); ascending-g strict->
// combine preserves jnp.argmax first-max semantics; LDS backtrack.
// b32 stride-1 reads (2 lanes/bank = free) — this access shape is at its
// structural LDS-pipe bound; b128 quad variants regress (per-dword decompose).
// ---------------------------------------------------------------------------
__global__ __launch_bounds__(1024) void cky_kernel(
    const float* __restrict__ scores,  // [64][256][256]
    uint8_t* __restrict__ Sws,         // [64][32896] packed triangular
    int* __restrict__ out)             // [2][64][256] int32
{
  const int b = blockIdx.x;
  const int t = threadIdx.x;
  const int n = Ss;
  const float* sc = scores + (long long)b * n * n;
  uint8_t* SP = Sws + (long long)b * 32896;

  __shared__ float Dch[32896];
  __shared__ float pv[1024];
  __shared__ uint8_t pmv[1024];
  __shared__ int stk[256];

  if (t < n) {
    out[b * n + t] = 0;
    out[Bb * n + b * n + t] = 0;
    Dch[t] = 0.f;
  }
  __syncthreads();

  int offw = n;  // off(1)
  for (int w = 1; w < n; ++w) {
    const int nv = n - w;
    const int lgT = (nv > 128) ? 8 : ((nv > 64) ? 7 : 6);
    const int T = 1 << lgT;
    const int G = 1024 >> lgT;
    const int g = t >> lgT;
    const int u = t & (T - 1);

    float scv = 0.f;
    if (t < nv) scv = sc[t * (n + 1) + w];

    const int wG = (w + G - 1) >> (10 - lgT);
    const int ml = g * wG;
    const int mh = (w < ml + wG) ? w : (ml + wG);
    float best = -3.0e38f;
    int bmv = 0;
    if (u < nv && ml < mh) {
      int al = ml * n - ((ml * (ml - 1)) >> 1) + u;
      const int kr = w - 1 - ml;
      int ar = kr * n - ((kr * (kr - 1)) >> 1) + u + ml + 1;
      int dl = n - ml;
      int dr = n - w + ml + 1;
#pragma unroll 4
      for (int m = ml; m < mh; ++m) {
        float c = Dch[al] + Dch[ar];
        if (c > best) {
          best = c;
          bmv = m;
        }
        al += dl;
        ar -= dr;
        --dl;
        ++dr;
      }
    }
    pv[t] = best;
    pmv[t] = (uint8_t)bmv;
    __syncthreads();

    if (t < nv) {
      float bb = pv[t];
      int bm = pmv[t];
      for (int g2 = 1; g2 < G; ++g2) {
        float v = pv[g2 * T + t];
        if (v > bb) {
          bb = v;
          bm = pmv[g2 * T + t];
        }
      }
      Dch[offw + t] = scv + bb;
      SP[offw + t] = (uint8_t)bm;
    }
    __syncthreads();
    offw += nv;
  }

  uint8_t* spl = (uint8_t*)Dch;
  for (int idx = t; idx < 32896; idx += 1024) spl[idx] = SP[idx];
  __syncthreads();
  if (t == 0) {
    int top = 0;
    stk[top++] = (0 << 16) | (n - 1);
    int cnt = 0;
    for (int step = 0; step < n - 1; ++step) {
      if (top > 0) {
        int ij = stk[--top];
        int ii = ij >> 16, jj = ij & 0xffff;
        out[b * n + cnt] = ii;
        out[Bb * n + b * n + cnt] = jj;
        ++cnt;
        int k = jj - ii;
        int s = ii + (int)spl[k * n - ((k * (k - 1)) >> 1) + ii];
        stk[top] = (ii << 16) | s;
        if (s > ii) ++top;
        stk[top] = ((s + 1) << 16) | jj;
        if (jj > s + 1) ++top;
      }
    }
  }
}

// ---------------------------------------------------------------------------
// Launch
// ---------------------------------------------------------------------------
extern "C" void kernel_launch(void* const* d_in, const int* in_sizes, int n_in,
                              void* d_out, int out_size, void* d_ws,
                              size_t ws_size, hipStream_t stream) {
  const float* X = (const float*)d_in[0];     // [64,256,1024]
  const float* Wl = (const float*)d_in[2];    // [1024,1024]
  const float* bl = (const float*)d_in[3];    // [1024]
  const float* Wr = (const float*)d_in[4];
  const float* br = (const float*)d_in[5];
  const float* Wbil = (const float*)d_in[6];  // [1025,1025]
  const float* bbil = (const float*)d_in[7];  // scalar
  int* out = (int*)d_out;

  // workspace layout
  float* ws = (float*)d_ws;
  float* lefts = ws;                          // 16777216 f
  float* rights = lefts + 16777216;           // 16777216 f
  float* tmpA = rights + 16777216;            // 16777216 f
  float* scoresP = tmpA + 16777216;           // 4194304 f
  float* tmpb = scoresP + 4194304;            // 16384 f
  float* browp = tmpb + 16384;                // 1024 f
  float* bcolp = browp + 1024;                // 1024 f
  float* cornerp = bcolp + 1024;              // 4 f
  unsigned short* Wlrt = (unsigned short*)(cornerp + 4);  // 3 x 2M bf16
  unsigned short* Wct = Wlrt + 3LL * 2097152;             // 3 x 1M bf16
  uint8_t* SPp = (uint8_t*)(Wct + 3LL * 1048576);         // 64x32896 u8

  // weight splits (+ Wbil bias vectors)
  splitw_kernel<<<dim3(4096), 256, 0, stream>>>(Wl, 1024, Wlrt, 2097152);
  splitw_kernel<<<dim3(4096), 256, 0, stream>>>(Wr, 1024, Wlrt + 1048576,
                                                2097152);
  splitw_kernel<<<dim3(4096), 256, 0, stream>>>(Wbil, 1025, Wct, 1048576);
  bilvec_kernel<<<dim3(4), 256, 0, stream>>>(Wbil, browp, bcolp, cornerp);

  // fused lefts|rights GEMM: N=2048
  dim3 gLR(16, 128);
  gemm_mfma_kernel<true><<<gLR, 256, 0, stream>>>(X, Wlrt, 2097152LL, lefts,
                                                  rights, bl, br);

  colvec_kernel<<<dim3(16384), 64, 0, stream>>>(lefts, bcolp, cornerp, tmpb);

  dim3 gA(8, 128);
  gemm_mfma_kernel<false><<<gA, 256, 0, stream>>>(lefts, Wct, 1048576LL, tmpA,
                                                  tmpA, browp, browp);

  dim3 g3(2, 2, 64);
  gemmnt_mfma_kernel<<<g3, 256, 0, stream>>>(tmpA, rights, scoresP, tmpb,
                                             bbil);

  cky_kernel<<<dim3(Bb), dim3(1024), 0, stream>>>(scoresP, SPp, out);
}

// Round 8
// 1239.458 us; speedup vs baseline: 1.6583x; 1.1665x over previous
//
#include <hip/hip_runtime.h>
#include <cstdint>

// ---------------------------------------------------------------------------
// ChartParser: span scores + per-batch CKY DP + backtrack.
// B=64, S=256, D=H=1024. Output: int32 [2][B][S] (lefts then rights).
// Round 8: (a) GEMMs switch bf16x3-limb/6-product -> fp16x2-limb/4-product
// (same ~4e-6 error class, 2/3 the LDS+VALU+staging cost — GEMMs are
// LDS-pipe bound, not MFMA bound); (b) CKY pairs each lane with i and
// i+delta so both chart reads become ds_read2_b32 (2 dwords/instr, both
// halves lane-stride-1 = free 2-way) and m-group count doubles.
// ---------------------------------------------------------------------------

#define Bb 64
#define Ss 256
#define Dd 1024
#define Hh 1024

typedef __attribute__((ext_vector_type(8))) _Float16 f16x8;
typedef __attribute__((ext_vector_type(4))) float f32x4;

// x = h + l + delta, |delta| <= 2^-22 |x| (fp16 RNE twice)
__device__ __forceinline__ void split2(float x, unsigned short& h,
                                       unsigned short& l) {
  _Float16 hh = (_Float16)x;
  _Float16 ll = (_Float16)(x - (float)hh);
  h = __builtin_bit_cast(unsigned short, hh);
  l = __builtin_bit_cast(unsigned short, ll);
}

// ---------------------------------------------------------------------------
// Weight split+transpose: W fp32 [1024 k-rows, ld ldw] -> O fp16 [n][k],
// limb planes at +0, +plane.
// ---------------------------------------------------------------------------
__global__ __launch_bounds__(256) void splitw_kernel(
    const float* __restrict__ W, int ldw, unsigned short* __restrict__ O,
    long long plane) {
  int idx = blockIdx.x * 256 + threadIdx.x;  // n*1024 + k
  int n = idx >> 10, k = idx & 1023;
  float x = W[(long long)k * ldw + n];
  unsigned short h, l;
  split2(x, h, l);
  O[idx] = h;
  O[plane + idx] = l;
}

// Extract Wbil's bias row / col / corner.
__global__ __launch_bounds__(256) void bilvec_kernel(
    const float* __restrict__ Wbil, float* __restrict__ brow,
    float* __restrict__ bcol, float* __restrict__ corner) {
  int i = blockIdx.x * 256 + threadIdx.x;  // 0..1023
  brow[i] = Wbil[1024 * 1025 + i];
  bcol[i] = Wbil[i * 1025 + 1024];
  if (i == 0) corner[0] = Wbil[1024 * 1025 + 1024];
}

__device__ __forceinline__ void pack8(char* dst, const unsigned short* v) {
  uint4 u;
  u.x = (unsigned)v[0] | ((unsigned)v[1] << 16);
  u.y = (unsigned)v[2] | ((unsigned)v[3] << 16);
  u.z = (unsigned)v[4] | ((unsigned)v[5] << 16);
  u.w = (unsigned)v[6] | ((unsigned)v[7] << 16);
  *(uint4*)dst = u;
}

// split 16 fp32 -> 2x16 fp16 limbs, store (swizzled) to 2 LDS planes
__device__ __forceinline__ void split_store16f(const float* xs, char* lds,
                                               int base, int wa0, int wa1) {
  unsigned short hs[16], ls[16];
#pragma unroll
  for (int i = 0; i < 16; ++i) split2(xs[i], hs[i], ls[i]);
  pack8(&lds[base + wa0], hs);
  pack8(&lds[base + wa1], hs + 8);
  pack8(&lds[base + 8192 + wa0], ls);
  pack8(&lds[base + 8192 + wa1], ls + 8);
}

// 4-product accumulate for one nf column: (ah+al)x(bh+bl), all kept
#define MFMA4(afv, bh, blv, accs, nf)                                        \
  {                                                                          \
    _Pragma("unroll") for (int mf = 0; mf < 4; ++mf) accs[mf][nf] =          \
        __builtin_amdgcn_mfma_f32_16x16x32_f16(afv[0][mf], bh,               \
                                               accs[mf][nf], 0, 0, 0);       \
    _Pragma("unroll") for (int mf = 0; mf < 4; ++mf) accs[mf][nf] =          \
        __builtin_amdgcn_mfma_f32_16x16x32_f16(afv[0][mf], blv,              \
                                               accs[mf][nf], 0, 0, 0);       \
    _Pragma("unroll") for (int mf = 0; mf < 4; ++mf) accs[mf][nf] =          \
        __builtin_amdgcn_mfma_f32_16x16x32_f16(afv[1][mf], bh,               \
                                               accs[mf][nf], 0, 0, 0);       \
    _Pragma("unroll") for (int mf = 0; mf < 4; ++mf) accs[mf][nf] =          \
        __builtin_amdgcn_mfma_f32_16x16x32_f16(afv[1][mf], blv,              \
                                               accs[mf][nf], 0, 0, 0);       \
  }

// ---------------------------------------------------------------------------
// MFMA GEMM (NN): out = act(A[M,1024]_fp32 * Bsp + bias). Bsp pre-split fp16
// [n][k], limb planes at stride bplane. Tile 128x128, BK=32, 256 threads,
// wave-tile 64x64 (4x4 frags of mfma_f32_16x16x32_f16). LDS 32KB:
// Ah@0, Al@8192, Bh@16384, Bl@24576; 16B-chunk XOR swizzle
// phi(r)=((r>>1)^(r>>3))&3 (proven conflict-clean, rounds 5-7).
// If n0 >= 1024 the block writes C1/bias1 at col-1024 (fused dual output).
// ---------------------------------------------------------------------------
template <bool LEAKY>
__global__ __launch_bounds__(256, 3) void gemm_mfma_kernel(
    const float* __restrict__ A, const unsigned short* __restrict__ Bsp,
    long long bplane, float* __restrict__ C0, float* __restrict__ C1,
    const float* __restrict__ bias0, const float* __restrict__ bias1) {
  const int m0 = blockIdx.y * 128;
  const int n0 = blockIdx.x * 128;
  __shared__ __align__(16) char lds[32768];
  const int t = threadIdx.x;
  const int L = t & 63, w = t >> 6, q = L >> 4, l15 = L & 15;

  const int ar = t >> 1, ah = t & 1;
  const float* aptr = A + (long long)(m0 + ar) * 1024 + ah * 16;
  const int phiA = ((ar >> 1) ^ (ar >> 3)) & 3;
  const int wa0 = ar * 64 + (((2 * ah + 0) ^ phiA) << 4);
  const int wa1 = ar * 64 + (((2 * ah + 1) ^ phiA) << 4);

  int offA0[4], offB0[4];
#pragma unroll
  for (int f = 0; f < 4; ++f) {
    int rowa = ((w & 1) << 6) + (f << 4) + l15;
    offA0[f] = rowa * 64 + ((q ^ (((rowa >> 1) ^ (rowa >> 3)) & 3)) << 4);
    int rowb = ((w >> 1) << 6) + (f << 4) + l15;
    offB0[f] =
        16384 + rowb * 64 + ((q ^ (((rowb >> 1) ^ (rowb >> 3)) & 3)) << 4);
  }

  f32x4 acc[4][4];
#pragma unroll
  for (int i = 0; i < 4; ++i)
#pragma unroll
    for (int j = 0; j < 4; ++j) acc[i][j] = (f32x4){0.f, 0.f, 0.f, 0.f};

  for (int k0 = 0; k0 < 1024; k0 += 32) {
    // B staging: 4 x 16B per thread (pre-split fp16, swizzled dest)
#pragma unroll
    for (int j = 0; j < 4; ++j) {
      int fc = t + (j << 8);  // 0..1023
      int s = fc >> 9, r = (fc >> 2) & 127, sc = fc & 3;
      const unsigned short* bs = Bsp + s * bplane;
      uint4 bv =
          *(const uint4*)(bs + (long long)(n0 + r) * 1024 + k0 + (sc << 3));
      int phi = ((r >> 1) ^ (r >> 3)) & 3;
      *(uint4*)&lds[16384 + s * 8192 + r * 64 + ((sc ^ phi) << 4)] = bv;
    }
    // A staging: 16 fp32 -> 2 x 16 fp16 limbs
    {
      float4 a0 = *(const float4*)(aptr + k0);
      float4 a1 = *(const float4*)(aptr + k0 + 4);
      float4 a2 = *(const float4*)(aptr + k0 + 8);
      float4 a3 = *(const float4*)(aptr + k0 + 12);
      float xs[16] = {a0.x, a0.y, a0.z, a0.w, a1.x, a1.y, a1.z, a1.w,
                      a2.x, a2.y, a2.z, a2.w, a3.x, a3.y, a3.z, a3.w};
      split_store16f(xs, lds, 0, wa0, wa1);
    }
    __syncthreads();
    f16x8 af[2][4];
#pragma unroll
    for (int s = 0; s < 2; ++s)
#pragma unroll
      for (int f = 0; f < 4; ++f)
        af[s][f] = *(const f16x8*)&lds[s * 8192 + offA0[f]];
#pragma unroll
    for (int nf = 0; nf < 4; ++nf) {
      f16x8 bh = *(const f16x8*)&lds[offB0[nf]];
      f16x8 bl = *(const f16x8*)&lds[8192 + offB0[nf]];
      MFMA4(af, bh, bl, acc, nf);
    }
    __syncthreads();
  }

  const bool isR = (n0 >= 1024);
  float* Co = isR ? C1 : C0;
  const float* bp = isR ? bias1 : bias0;
  const int nc0 = n0 & 1023;
#pragma unroll
  for (int nf = 0; nf < 4; ++nf) {
    int col = nc0 + ((w >> 1) << 6) + (nf << 4) + l15;
    float bz = bp[col];
#pragma unroll
    for (int mf = 0; mf < 4; ++mf) {
#pragma unroll
      for (int r = 0; r < 4; ++r) {
        int row = m0 + ((w & 1) << 6) + (mf << 4) + (q << 2) + r;
        float x = acc[mf][nf][r] + bz;
        if (LEAKY) x = (x > 0.f) ? x : 0.1f * x;
        Co[(long long)row * 1024 + col] = x;
      }
    }
  }
}

// ---------------------------------------------------------------------------
// Batched NT GEMM on MFMA: C[b] = tmpA[b] * rights[b]^T + rowAdd + scal.
// Both operands fp32, split in-kernel to fp16x2. Tile 128x128, grid (2,2,64).
// ---------------------------------------------------------------------------
__global__ __launch_bounds__(256, 3) void gemmnt_mfma_kernel(
    const float* __restrict__ A, const float* __restrict__ B,
    float* __restrict__ C, const float* __restrict__ rowAdd,
    const float* __restrict__ scal) {
  const int bz = blockIdx.z;
  A += (long long)bz * 256 * 1024;
  B += (long long)bz * 256 * 1024;
  C += (long long)bz * 256 * 256;
  const int m0 = blockIdx.y * 128;
  const int n0 = blockIdx.x * 128;
  __shared__ __align__(16) char lds[32768];
  const int t = threadIdx.x;
  const int L = t & 63, w = t >> 6, q = L >> 4, l15 = L & 15;

  const int ar = t >> 1, ah = t & 1;
  const float* aptr = A + (long long)(m0 + ar) * 1024 + ah * 16;
  const float* bptr = B + (long long)(n0 + ar) * 1024 + ah * 16;
  const int phiA = ((ar >> 1) ^ (ar >> 3)) & 3;
  const int wa0 = ar * 64 + (((2 * ah + 0) ^ phiA) << 4);
  const int wa1 = ar * 64 + (((2 * ah + 1) ^ phiA) << 4);

  int offA0[4], offB0[4];
#pragma unroll
  for (int f = 0; f < 4; ++f) {
    int rowa = ((w & 1) << 6) + (f << 4) + l15;
    offA0[f] = rowa * 64 + ((q ^ (((rowa >> 1) ^ (rowa >> 3)) & 3)) << 4);
    int rowb = ((w >> 1) << 6) + (f << 4) + l15;
    offB0[f] =
        16384 + rowb * 64 + ((q ^ (((rowb >> 1) ^ (rowb >> 3)) & 3)) << 4);
  }

  f32x4 acc[4][4];
#pragma unroll
  for (int i = 0; i < 4; ++i)
#pragma unroll
    for (int j = 0; j < 4; ++j) acc[i][j] = (f32x4){0.f, 0.f, 0.f, 0.f};

  for (int k0 = 0; k0 < 1024; k0 += 32) {
    {
      float4 a0 = *(const float4*)(aptr + k0);
      float4 a1 = *(const float4*)(aptr + k0 + 4);
      float4 a2 = *(const float4*)(aptr + k0 + 8);
      float4 a3 = *(const float4*)(aptr + k0 + 12);
      float xs[16] = {a0.x, a0.y, a0.z, a0.w, a1.x, a1.y, a1.z, a1.w,
                      a2.x, a2.y, a2.z, a2.w, a3.x, a3.y, a3.z, a3.w};
      split_store16f(xs, lds, 0, wa0, wa1);
      float4 b0 = *(const float4*)(bptr + k0);
      float4 b1 = *(const float4*)(bptr + k0 + 4);
      float4 b2 = *(const float4*)(bptr + k0 + 8);
      float4 b3 = *(const float4*)(bptr + k0 + 12);
      float ys[16] = {b0.x, b0.y, b0.z, b0.w, b1.x, b1.y, b1.z, b1.w,
                      b2.x, b2.y, b2.z, b2.w, b3.x, b3.y, b3.z, b3.w};
      split_store16f(ys, lds, 16384, wa0, wa1);
    }
    __syncthreads();
    f16x8 af[2][4];
#pragma unroll
    for (int s = 0; s < 2; ++s)
#pragma unroll
      for (int f = 0; f < 4; ++f)
        af[s][f] = *(const f16x8*)&lds[s * 8192 + offA0[f]];
#pragma unroll
    for (int nf = 0; nf < 4; ++nf) {
      f16x8 bh = *(const f16x8*)&lds[offB0[nf]];
      f16x8 bl = *(const f16x8*)&lds[8192 + offB0[nf]];
      MFMA4(af, bh, bl, acc, nf);
    }
    __syncthreads();
  }

  const float sc_add = scal[0];
#pragma unroll
  for (int mf = 0; mf < 4; ++mf) {
#pragma unroll
    for (int r = 0; r < 4; ++r) {
      int row = m0 + ((w & 1) << 6) + (mf << 4) + (q << 2) + r;
      float radd = sc_add + rowAdd[(long long)bz * 256 + row];
#pragma unroll
      for (int nf = 0; nf < 4; ++nf) {
        int col = n0 + ((w >> 1) << 6) + (nf << 4) + l15;
        C[(long long)row * 256 + col] = acc[mf][nf][r] + radd;
      }
    }
  }
}

// ---------------------------------------------------------------------------
// tmpb[i] = dot(lefts[i,:], Wbil[0:H, H]) + Wbil[H,H].  One wave per row.
// ---------------------------------------------------------------------------
__global__ __launch_bounds__(64) void colvec_kernel(
    const float* __restrict__ lefts, const float* __restrict__ bcol,
    const float* __restrict__ corner, float* __restrict__ tmpb) {
  int row = blockIdx.x;
  int lane = threadIdx.x;
  const float* a = lefts + (long long)row * Hh;
  float s = 0.f;
#pragma unroll
  for (int h = lane; h < Hh; h += 64) s = fmaf(a[h], bcol[h], s);
#pragma unroll
  for (int off = 32; off > 0; off >>= 1) s += __shfl_down(s, off, 64);
  if (lane == 0) tmpb[row] = s + corner[0];
}

// ---------------------------------------------------------------------------
// CKY + backtrack. One block per batch, 1024 threads. Chart in LDS, packed
// triangular diag-major (r3 layout). Each lane covers i = u and i+delta
// (delta=128 for w<128, 64 for 128<=w<192, none after): both chart reads
// become same-base dword pairs -> ds_read2_b32; each half is lane-stride-1
// (free 2-way). m-groups G = 8/16/16. Garbage lanes (i+delta >= nv) write to
// partial slots >= nv which the combine never reads; all paired reads stay
// inside the 32896-float chart. Ascending-(g,m) strict-> combine preserves
// jnp.argmax first-max semantics. Backtrack from LDS.
// ---------------------------------------------------------------------------
__global__ __launch_bounds__(1024) void cky_kernel(
    const float* __restrict__ scores,  // [64][256][256]
    uint8_t* __restrict__ Sws,         // [64][32896] packed triangular
    int* __restrict__ out)             // [2][64][256] int32
{
  const int b = blockIdx.x;
  const int t = threadIdx.x;
  const int n = Ss;
  const float* sc = scores + (long long)b * n * n;
  uint8_t* SP = Sws + (long long)b * 32896;

  __shared__ float Dch[32896];
  __shared__ float pv[2048];
  __shared__ uint8_t pmv[2048];
  __shared__ int stk[256];

  if (t < n) {
    out[b * n + t] = 0;
    out[Bb * n + b * n + t] = 0;
    Dch[t] = 0.f;
  }
  __syncthreads();

  int offw = n;  // off(1)
  for (int w = 1; w < n; ++w) {
    const int nv = n - w;
    int lgT, delta, lgS;
    if (nv > 128) {        // R1: T=128, G=8, pair (u, u+128)
      lgT = 7; delta = 128; lgS = 8;
    } else if (nv > 64) {  // R2: T=64, G=16, pair (u, u+64)
      lgT = 6; delta = 64; lgS = 7;
    } else {               // R3: T=64, G=16, single
      lgT = 6; delta = 0; lgS = 7;
    }
    const int G = 1024 >> lgT;
    const int g = t >> lgT;
    const int u = t & ((1 << lgT) - 1);

    float scv = 0.f;
    if (t < nv) scv = sc[t * (n + 1) + w];

    const int wG = (w + G - 1) >> (10 - lgT);  // ceil(w/G)
    const int ml = g * wG;
    const int mh = (w < ml + wG) ? w : (ml + wG);
    float b0 = -3.0e38f, b1 = -3.0e38f;
    int m0i = 0, m1i = 0;
    if (u < nv && ml < mh) {
      int al = ml * n - ((ml * (ml - 1)) >> 1) + u;
      const int kr = w - 1 - ml;
      int ar = kr * n - ((kr * (kr - 1)) >> 1) + u + ml + 1;
      int dl = n - ml;
      int dr = n - w + ml + 1;
      if (delta) {
#pragma unroll 2
        for (int m = ml; m < mh; ++m) {
          float l0 = Dch[al], l1 = Dch[al + delta];   // -> ds_read2_b32
          float r0 = Dch[ar], r1 = Dch[ar + delta];   // -> ds_read2_b32
          float c0 = l0 + r0, c1 = l1 + r1;
          if (c0 > b0) { b0 = c0; m0i = m; }  // strict > = first max
          if (c1 > b1) { b1 = c1; m1i = m; }
          al += dl;
          ar -= dr;
          --dl;
          ++dr;
        }
      } else {
#pragma unroll 4
        for (int m = ml; m < mh; ++m) {
          float c = Dch[al] + Dch[ar];
          if (c > b0) { b0 = c; m0i = m; }
          al += dl;
          ar -= dr;
          --dl;
          ++dr;
        }
      }
    }
    const int sbase = (g << (lgS + (delta ? 1 : 0) - (delta ? 0 : 0)));  // g*sstr
    // slot stride = 2^lgS when paired covers 2*T, else 2^lgS as well:
    // R1: sstr=256=2^(lgS)   (lgS=8), R2/R3: sstr=128=2^(lgS) (lgS=7)
    pv[(g << lgS) + u] = b0;
    pmv[(g << lgS) + u] = (uint8_t)m0i;
    if (delta) {
      pv[(g << lgS) + u + delta] = b1;
      pmv[(g << lgS) + u + delta] = (uint8_t)m1i;
    }
    __syncthreads();

    if (t < nv) {
      float bb = pv[t];
      int bm = pmv[t];
      for (int g2 = 1; g2 < G; ++g2) {
        float v = pv[(g2 << lgS) + t];
        if (v > bb) {  // ascending g + strict > = first max overall
          bb = v;
          bm = pmv[(g2 << lgS) + t];
        }
      }
      Dch[offw + t] = scv + bb;
      SP[offw + t] = (uint8_t)bm;
    }
    __syncthreads();
    offw += nv;
  }

  uint8_t* spl = (uint8_t*)Dch;
  for (int idx = t; idx < 32896; idx += 1024) spl[idx] = SP[idx];
  __syncthreads();
  if (t == 0) {
    int top = 0;
    stk[top++] = (0 << 16) | (n - 1);
    int cnt = 0;
    for (int step = 0; step < n - 1; ++step) {
      if (top > 0) {
        int ij = stk[--top];
        int ii = ij >> 16, jj = ij & 0xffff;
        out[b * n + cnt] = ii;
        out[Bb * n + b * n + cnt] = jj;
        ++cnt;
        int k = jj - ii;
        int s = ii + (int)spl[k * n - ((k * (k - 1)) >> 1) + ii];
        stk[top] = (ii << 16) | s;
        if (s > ii) ++top;
        stk[top] = ((s + 1) << 16) | jj;
        if (jj > s + 1) ++top;
      }
    }
  }
}

// ---------------------------------------------------------------------------
// Launch
// ---------------------------------------------------------------------------
extern "C" void kernel_launch(void* const* d_in, const int* in_sizes, int n_in,
                              void* d_out, int out_size, void* d_ws,
                              size_t ws_size, hipStream_t stream) {
  const float* X = (const float*)d_in[0];     // [64,256,1024]
  const float* Wl = (const float*)d_in[2];    // [1024,1024]
  const float* bl = (const float*)d_in[3];    // [1024]
  const float* Wr = (const float*)d_in[4];
  const float* br = (const float*)d_in[5];
  const float* Wbil = (const float*)d_in[6];  // [1025,1025]
  const float* bbil = (const float*)d_in[7];  // scalar
  int* out = (int*)d_out;

  // workspace layout
  float* ws = (float*)d_ws;
  float* lefts = ws;                          // 16777216 f
  float* rights = lefts + 16777216;           // 16777216 f
  float* tmpA = rights + 16777216;            // 16777216 f
  float* scoresP = tmpA + 16777216;           // 4194304 f
  float* tmpb = scoresP + 4194304;            // 16384 f
  float* browp = tmpb + 16384;                // 1024 f
  float* bcolp = browp + 1024;                // 1024 f
  float* cornerp = bcolp + 1024;              // 4 f
  unsigned short* Wlrt = (unsigned short*)(cornerp + 4);  // 2 x 2M fp16
  unsigned short* Wct = Wlrt + 2LL * 2097152;             // 2 x 1M fp16
  uint8_t* SPp = (uint8_t*)(Wct + 2LL * 1048576);         // 64x32896 u8

  // weight splits (+ Wbil bias vectors)
  splitw_kernel<<<dim3(4096), 256, 0, stream>>>(Wl, 1024, Wlrt, 2097152);
  splitw_kernel<<<dim3(4096), 256, 0, stream>>>(Wr, 1024, Wlrt + 1048576,
                                                2097152);
  splitw_kernel<<<dim3(4096), 256, 0, stream>>>(Wbil, 1025, Wct, 1048576);
  bilvec_kernel<<<dim3(4), 256, 0, stream>>>(Wbil, browp, bcolp, cornerp);

  // fused lefts|rights GEMM: N=2048
  dim3 gLR(16, 128);
  gemm_mfma_kernel<true><<<gLR, 256, 0, stream>>>(X, Wlrt, 2097152LL, lefts,
                                                  rights, bl, br);

  colvec_kernel<<<dim3(16384), 64, 0, stream>>>(lefts, bcolp, cornerp, tmpb);

  dim3 gA(8, 128);
  gemm_mfma_kernel<false><<<gA, 256, 0, stream>>>(lefts, Wct, 1048576LL, tmpA,
                                                  tmpA, browp, browp);

  dim3 g3(2, 2, 64);
  gemmnt_mfma_kernel<<<g3, 256, 0, stream>>>(tmpA, rights, scoresP, tmpb,
                                             bbil);

  cky_kernel<<<dim3(Bb), dim3(1024), 0, stream>>>(scoresP, SPp, out);
}